// Round 4
// baseline (604.384 us; speedup 1.0000x reference)
//
#include <hip/hip_runtime.h>

// Entmax-1.5 over last axis. tau* is the root of
//   f(tau) = sum_i max(x_i - tau, 0)^2 - 1   (convex, piecewise quadratic, decreasing)
// Piecewise-exact (Michelot-style) root iteration:
//   u = (F-1) / (G + sqrt(G^2 - K*(F-1))),  F = sum y^2, G = sum y, K = #{y>0}
//
// Round-3 finding: duration is invariant (~205 us) across 1-row / 2-row-interleaved
// variants. Model check: mem-at-ceiling (293k cyc) + VALU (146k cyc) ~= measured
// 487k cyc -> memory and compute run IN SERIES. Every prior version had the phase
// structure [issue loads -> stall -> VALU-only solve -> store]: zero memory in
// flight during the solve.
//
// Fix: software pipeline across rows within a wave. Each wave owns 8 consecutive
// rows; row n+1's 16 global_load_dwordx4 are issued right after row n's raw regs
// are consumed, so HBM latency hides under row n's solve and the memory pipe sees
// continuous demand. Grid 1024 blocks x 4 waves x 8 rows = 32768 (persistent,
// 4 blocks/CU). Kept: packed-fp32 math, ballot+popc K, fused first step.

#define NEG_FILL (-1.0e4f)

typedef float float2v __attribute__((ext_vector_type(2)));

static constexpr int S_DIM = 2048;
static constexpr int WAVES_PER_BLOCK = 4;       // 256-thread blocks
static constexpr int ROWS_PER_WAVE = 8;         // pipelined sequentially per wave
static constexpr int ELEMS = S_DIM / 64;        // 32 floats per lane per row
static constexpr int VEC = ELEMS / 4;           // 8 float4 loads per lane per row
static constexpr int VEC2 = ELEMS / 2;          // 16 float2 chunks per lane per row

__global__ __launch_bounds__(256) void entmax15_kernel(
    const float* __restrict__ scores,
    const int*   __restrict__ mask,
    float*       __restrict__ out,
    int nrows)
{
    const int lane = threadIdx.x & 63;
    const int wave = threadIdx.x >> 6;
    const int gw   = blockIdx.x * WAVES_PER_BLOCK + wave;   // global wave id
    const int row0 = gw * ROWS_PER_WAVE;
    if (row0 >= nrows) return;

    // ---- raw prefetch registers (row n+1 lives here while row n is solved) ----
    float4 sreg[VEC];
    int4   mreg[VEC];

    // prologue: issue loads for row0
    {
        const float4* __restrict__ s = (const float4*)(scores + (size_t)row0 * S_DIM);
        const int4*   __restrict__ m = (const int4*)(mask   + (size_t)row0 * S_DIM);
#pragma unroll
        for (int j = 0; j < VEC; ++j) {
            sreg[j] = s[lane + 64 * j];
            mreg[j] = m[lane + 64 * j];
        }
    }

    const float2v h05   = {0.5f, 0.5f};
    const float2v one2  = {1.0f, 1.0f};
    const float2v zero2 = {0.0f, 0.0f};

#pragma unroll 1
    for (int r = 0; r < ROWS_PER_WAVE; ++r) {
        const int row = row0 + r;
        if (row >= nrows) break;

        // ---- consume raw regs: mask-select + row max (forces vmcnt wait here) ----
        float x[ELEMS];
        float rmax = -3.402823466e38f;
#pragma unroll
        for (int j = 0; j < VEC; ++j) {
            const float4 s = sreg[j];
            const int4   m = mreg[j];
            float v0 = m.x ? s.x : NEG_FILL;
            float v1 = m.y ? s.y : NEG_FILL;
            float v2 = m.z ? s.z : NEG_FILL;
            float v3 = m.w ? s.w : NEG_FILL;
            x[4 * j + 0] = v0;
            x[4 * j + 1] = v1;
            x[4 * j + 2] = v2;
            x[4 * j + 3] = v3;
            rmax = fmaxf(rmax, fmaxf(fmaxf(v0, v1), fmaxf(v2, v3)));
        }

        // ---- issue next row's loads NOW; they fly during the solve below ----
        if (r + 1 < ROWS_PER_WAVE && row + 1 < nrows) {
            const float4* __restrict__ sn = (const float4*)(scores + (size_t)(row + 1) * S_DIM);
            const int4*   __restrict__ mn = (const int4*)(mask   + (size_t)(row + 1) * S_DIM);
#pragma unroll
            for (int j = 0; j < VEC; ++j) {
                sreg[j] = sn[lane + 64 * j];
                mreg[j] = mn[lane + 64 * j];
            }
        }

        // ---- rmax butterfly ----
#pragma unroll
        for (int off = 32; off >= 1; off >>= 1)
            rmax = fmaxf(rmax, __shfl_xor(rmax, off, 64));

        // ---- alpha=1.5 transform fused with first exact step at tau0=-1 ----
        // x = (x - max)*0.5  =>  max(x)==0, tau* in [-1, 0).  At tau=-1: d = x+1.
        const float2v sh2 = {-0.5f * rmax, -0.5f * rmax};
        float2v* xv = (float2v*)x;

        float2v F2 = zero2, G2 = zero2;
        int K = 0;
#pragma unroll
        for (int i = 0; i < VEC2; ++i) {
            float2v t = __builtin_elementwise_fma(xv[i], h05, sh2);   // v_pk_fma_f32
            xv[i] = t;
            float2v d = t + one2;
            float2v y = __builtin_elementwise_max(d, zero2);
            F2 = __builtin_elementwise_fma(y, y, F2);
            G2 = G2 + y;
            K += __popcll(__ballot(d.x > 0.0f));
            K += __popcll(__ballot(d.y > 0.0f));
        }

        float2v FG;
        FG.x = F2.x + F2.y;
        FG.y = G2.x + G2.y;
#pragma unroll
        for (int off = 32; off >= 1; off >>= 1) {
            float2v t;
            t.x = __shfl_xor(FG.x, off, 64);
            t.y = __shfl_xor(FG.y, off, 64);
            FG += t;
        }

        float c     = FG.x - 1.0f;                     // F - 1 (>= 0 from below)
        float disc  = fmaf(FG.y, FG.y, -(float)K * c); // G^2 - K*(F-1)
        float denom = (disc > 0.0f) ? (FG.y + sqrtf(disc)) : (2.0f * FG.y);
        float u     = c / denom;
        float tau   = -1.0f + u;

        // ---- remaining piecewise-exact iterations (wave-uniform break) ----
#pragma unroll 1
        for (int it = 1; it < 16 && fabsf(u) > 2e-7f; ++it) {
            const float2v t2 = {tau, tau};
            F2 = zero2; G2 = zero2; K = 0;
#pragma unroll
            for (int i = 0; i < VEC2; ++i) {
                float2v d = xv[i] - t2;
                float2v y = __builtin_elementwise_max(d, zero2);
                F2 = __builtin_elementwise_fma(y, y, F2);
                G2 = G2 + y;
                K += __popcll(__ballot(d.x > 0.0f));
                K += __popcll(__ballot(d.y > 0.0f));
            }
            FG.x = F2.x + F2.y;
            FG.y = G2.x + G2.y;
#pragma unroll
            for (int off = 32; off >= 1; off >>= 1) {
                float2v t;
                t.x = __shfl_xor(FG.x, off, 64);
                t.y = __shfl_xor(FG.y, off, 64);
                FG += t;
            }
            c     = FG.x - 1.0f;
            disc  = fmaf(FG.y, FG.y, -(float)K * c);
            denom = (disc > 0.0f) ? (FG.y + sqrtf(disc)) : (2.0f * FG.y);
            u     = c / denom;
            tau  += u;
        }

        // ---- epilogue: p = max(x - tau, 0)^2, coalesced float4 stores ----
        float4* __restrict__ orow = (float4*)(out + (size_t)row * S_DIM);
        const float2v t2 = {tau, tau};
#pragma unroll
        for (int j = 0; j < VEC; ++j) {
            float2v y0 = __builtin_elementwise_max(xv[2 * j]     - t2, zero2);
            float2v y1 = __builtin_elementwise_max(xv[2 * j + 1] - t2, zero2);
            float2v o0 = y0 * y0;
            float2v o1 = y1 * y1;
            float4 o;
            o.x = o0.x; o.y = o0.y; o.z = o1.x; o.w = o1.y;
            orow[lane + 64 * j] = o;
        }
    }
}

extern "C" void kernel_launch(void* const* d_in, const int* in_sizes, int n_in,
                              void* d_out, int out_size, void* d_ws, size_t ws_size,
                              hipStream_t stream) {
    const float* scores = (const float*)d_in[0];
    const int*   mask   = (const int*)d_in[1];
    float*       out    = (float*)d_out;

    const int nrows = in_sizes[0] / S_DIM;  // 32768
    const int rows_per_block = WAVES_PER_BLOCK * ROWS_PER_WAVE;
    const int grid = (nrows + rows_per_block - 1) / rows_per_block;

    entmax15_kernel<<<grid, 256, 0, stream>>>(scores, mask, out, nrows);
}

// Round 5
// 598.997 us; speedup vs baseline: 1.0090x; 1.0090x over previous
//
#include <hip/hip_runtime.h>
#include <stdint.h>

// Entmax-1.5 over last axis. tau* is the root of
//   f(tau) = sum_i max(x_i - tau, 0)^2 - 1   (convex, piecewise quadratic, decreasing)
// Piecewise-exact (Michelot-style) root iteration:
//   u = (F-1) / (G + sqrt(G^2 - K*(F-1))),  F = sum y^2, G = sum y, K = #{y>0}
//
// Round-4 finding: reg-prefetch pipeline was DEFEATED by the compiler (VGPR=80
// proves sreg/mreg never lived across the solve -> loads sunk to first use ->
// still serial [load|solve|store], same 205 us as every variant).
//
// Round-5 fix: async DMA pipeline the compiler cannot sink:
//   - __builtin_amdgcn_global_load_lds (width 16) stages row r+1 into a per-wave
//     16 KiB LDS bounce buffer while row r is solved from registers.
//   - completion via inline-asm counted s_waitcnt: at iter top the vmem queue is
//     FIFO [16 GLDS (older), 8 stores (newer)] -> vmcnt(8) drains exactly the
//     GLDS without stalling on store acks. vmcnt(0) only on the first iteration.
//   - sched_barrier(0) pins issue points; lgkmcnt(0) before re-staging ensures
//     the ds_reads retired before the buffer is overwritten.
// LDS 64 KiB/block -> 2 blocks/CU -> 8 waves/CU, each with 16 KiB continuously in
// flight (~128 KiB/CU outstanding >> ~9 KiB needed for peak HBM BW).
// Kept: packed-fp32 math, ballot+popc K, fused first step, wave-uniform break.

#define NEG_FILL (-1.0e4f)

typedef float float2v __attribute__((ext_vector_type(2)));

static constexpr int S_DIM = 2048;
static constexpr int WAVES_PER_BLOCK = 4;        // 256-thread blocks
static constexpr int ROWS_PER_WAVE = 8;          // grid = 32768/(4*8) = 1024 blocks
static constexpr int ELEMS = S_DIM / 64;         // 32 floats per lane per row
static constexpr int VEC = ELEMS / 4;            // 8 float4 chunks per lane per row
static constexpr int VEC2 = ELEMS / 2;           // 16 float2 chunks per lane per row
static constexpr int ROW_BYTES = S_DIM * 4;      // 8 KiB
static constexpr int WBUF_BYTES = 2 * ROW_BYTES; // 16 KiB per wave (scores+mask)

__global__ __launch_bounds__(256) void entmax15_kernel(
    const float* __restrict__ scores,
    const int*   __restrict__ mask,
    float*       __restrict__ out,
    int nrows)
{
    __shared__ char smem[WAVES_PER_BLOCK * WBUF_BYTES];  // 64 KiB

    const int lane = threadIdx.x & 63;
    const int wave = threadIdx.x >> 6;
    const int row0 = (blockIdx.x * WAVES_PER_BLOCK + wave) * ROWS_PER_WAVE;
    if (row0 >= nrows) return;

    char* wbuf = &smem[wave * WBUF_BYTES];
    const char* sbase = (const char*)scores;
    const char* mbase = (const char*)mask;

    // async-stage one row (scores 8 KiB + mask 8 KiB) into this wave's LDS buffer.
    // LDS dest is wave-uniform base + lane*16 (HW rule); global src is per-lane.
    // Layout: chunk j occupies bytes [j*1024, j*1024+1024), lane l at +l*16 --
    // i.e. float4 index (64*j + l), identical to the old direct-load pattern.
    auto stage = [&](int row) {
        const char* srow = sbase + (size_t)row * ROW_BYTES;
        const char* mrow = mbase + (size_t)row * ROW_BYTES;
#pragma unroll
        for (int j = 0; j < VEC; ++j) {
            __builtin_amdgcn_global_load_lds(
                (const __attribute__((address_space(1))) void*)(srow + lane * 16 + j * 1024),
                (__attribute__((address_space(3))) void*)(wbuf + j * 1024),
                16, 0, 0);
        }
#pragma unroll
        for (int j = 0; j < VEC; ++j) {
            __builtin_amdgcn_global_load_lds(
                (const __attribute__((address_space(1))) void*)(mrow + lane * 16 + j * 1024),
                (__attribute__((address_space(3))) void*)(wbuf + ROW_BYTES + j * 1024),
                16, 0, 0);
        }
    };

    // prologue: stage row0
    stage(row0);

    const float2v h05   = {0.5f, 0.5f};
    const float2v one2  = {1.0f, 1.0f};
    const float2v zero2 = {0.0f, 0.0f};

#pragma unroll 1
    for (int r = 0; r < ROWS_PER_WAVE; ++r) {
        const int row = row0 + r;
        if (row >= nrows) break;

        // ---- wait for this row's staged data.
        // r==0: only the 16 prologue GLDS are outstanding -> vmcnt(0).
        // r>0 : queue is FIFO [16 GLDS (older), 8 stores (newer)] -> vmcnt(8)
        //       retires all GLDS without waiting for store completion.
        if (r == 0) {
            asm volatile("s_waitcnt vmcnt(0)" ::: "memory");
        } else {
            asm volatile("s_waitcnt vmcnt(8)" ::: "memory");
        }
        __builtin_amdgcn_sched_barrier(0);

        // ---- LDS -> regs: mask-select + row max ----
        const float4* __restrict__ sl = (const float4*)wbuf;
        const int4*   __restrict__ ml = (const int4*)(wbuf + ROW_BYTES);
        float x[ELEMS];
        float rmax = -3.402823466e38f;
#pragma unroll
        for (int j = 0; j < VEC; ++j) {
            const float4 s = sl[64 * j + lane];
            const int4   m = ml[64 * j + lane];
            float v0 = m.x ? s.x : NEG_FILL;
            float v1 = m.y ? s.y : NEG_FILL;
            float v2 = m.z ? s.z : NEG_FILL;
            float v3 = m.w ? s.w : NEG_FILL;
            x[4 * j + 0] = v0;
            x[4 * j + 1] = v1;
            x[4 * j + 2] = v2;
            x[4 * j + 3] = v3;
            rmax = fmaxf(rmax, fmaxf(fmaxf(v0, v1), fmaxf(v2, v3)));
        }
        // all ds_reads retired before the buffer is re-staged
        asm volatile("s_waitcnt lgkmcnt(0)" ::: "memory");
        __builtin_amdgcn_sched_barrier(0);

        // ---- issue next row's DMA now; it flies during the solve below ----
        if (r + 1 < ROWS_PER_WAVE && row + 1 < nrows)
            stage(row + 1);
        __builtin_amdgcn_sched_barrier(0);

        // ---- rmax butterfly ----
#pragma unroll
        for (int off = 32; off >= 1; off >>= 1)
            rmax = fmaxf(rmax, __shfl_xor(rmax, off, 64));

        // ---- alpha=1.5 transform fused with first exact step at tau0=-1 ----
        // x = (x - max)*0.5  =>  max(x)==0, tau* in [-1, 0).  At tau=-1: d = x+1.
        const float2v sh2 = {-0.5f * rmax, -0.5f * rmax};
        float2v* xv = (float2v*)x;

        float2v F2 = zero2, G2 = zero2;
        int K = 0;
#pragma unroll
        for (int i = 0; i < VEC2; ++i) {
            float2v t = __builtin_elementwise_fma(xv[i], h05, sh2);   // v_pk_fma_f32
            xv[i] = t;
            float2v d = t + one2;
            float2v y = __builtin_elementwise_max(d, zero2);
            F2 = __builtin_elementwise_fma(y, y, F2);
            G2 = G2 + y;
            K += __popcll(__ballot(d.x > 0.0f));
            K += __popcll(__ballot(d.y > 0.0f));
        }

        float2v FG;
        FG.x = F2.x + F2.y;
        FG.y = G2.x + G2.y;
#pragma unroll
        for (int off = 32; off >= 1; off >>= 1) {
            float2v t;
            t.x = __shfl_xor(FG.x, off, 64);
            t.y = __shfl_xor(FG.y, off, 64);
            FG += t;
        }

        float c     = FG.x - 1.0f;                     // F - 1 (>= 0 from below)
        float disc  = fmaf(FG.y, FG.y, -(float)K * c); // G^2 - K*(F-1)
        float denom = (disc > 0.0f) ? (FG.y + sqrtf(disc)) : (2.0f * FG.y);
        float u     = c / denom;
        float tau   = -1.0f + u;

        // ---- remaining piecewise-exact iterations (wave-uniform break) ----
#pragma unroll 1
        for (int it = 1; it < 16 && fabsf(u) > 2e-7f; ++it) {
            const float2v t2 = {tau, tau};
            F2 = zero2; G2 = zero2; K = 0;
#pragma unroll
            for (int i = 0; i < VEC2; ++i) {
                float2v d = xv[i] - t2;
                float2v y = __builtin_elementwise_max(d, zero2);
                F2 = __builtin_elementwise_fma(y, y, F2);
                G2 = G2 + y;
                K += __popcll(__ballot(d.x > 0.0f));
                K += __popcll(__ballot(d.y > 0.0f));
            }
            FG.x = F2.x + F2.y;
            FG.y = G2.x + G2.y;
#pragma unroll
            for (int off = 32; off >= 1; off >>= 1) {
                float2v t;
                t.x = __shfl_xor(FG.x, off, 64);
                t.y = __shfl_xor(FG.y, off, 64);
                FG += t;
            }
            c     = FG.x - 1.0f;
            disc  = fmaf(FG.y, FG.y, -(float)K * c);
            denom = (disc > 0.0f) ? (FG.y + sqrtf(disc)) : (2.0f * FG.y);
            u     = c / denom;
            tau  += u;
        }

        // ---- epilogue: p = max(x - tau, 0)^2, 8x global_store_dwordx4 ----
        float4* __restrict__ orow = (float4*)(out + (size_t)row * S_DIM);
        const float2v t2 = {tau, tau};
#pragma unroll
        for (int j = 0; j < VEC; ++j) {
            float2v y0 = __builtin_elementwise_max(xv[2 * j]     - t2, zero2);
            float2v y1 = __builtin_elementwise_max(xv[2 * j + 1] - t2, zero2);
            float2v o0 = y0 * y0;
            float2v o1 = y1 * y1;
            float4 o;
            o.x = o0.x; o.y = o0.y; o.z = o1.x; o.w = o1.y;
            orow[64 * j + lane] = o;
        }
    }
}

extern "C" void kernel_launch(void* const* d_in, const int* in_sizes, int n_in,
                              void* d_out, int out_size, void* d_ws, size_t ws_size,
                              hipStream_t stream) {
    const float* scores = (const float*)d_in[0];
    const int*   mask   = (const int*)d_in[1];
    float*       out    = (float*)d_out;

    const int nrows = in_sizes[0] / S_DIM;  // 32768
    const int rows_per_block = WAVES_PER_BLOCK * ROWS_PER_WAVE;
    const int grid = (nrows + rows_per_block - 1) / rows_per_block;

    entmax15_kernel<<<grid, 256, 0, stream>>>(scores, mask, out, nrows);
}